// Round 1
// baseline (454.679 us; speedup 1.0000x reference)
//
#include <hip/hip_runtime.h>
#include <hip/hip_bf16.h>

typedef short bf16x8 __attribute__((ext_vector_type(8)));
typedef float f32x4  __attribute__((ext_vector_type(4)));

#define SEQ  2048
#define HD   64
#define LDT  72      // bf16 row stride for staged tiles (16B-aligned rows, 2-way-free banks)
#define TSTR 84      // per-wave T scratch stride (bf16)
#define PSTR 72      // per-wave P scratch stride (bf16)
#define OUT0 (16 * SEQ * HD)   // weights offset in d_out (output comes first)

__device__ __forceinline__ short f2bf(float x) {
    unsigned u = __float_as_uint(x);
    unsigned r = u + 0x7fffu + ((u >> 16) & 1u);   // RNE
    return (short)(r >> 16);
}
__device__ __forceinline__ float bf2f(short s) {
    return __uint_as_float(((unsigned)(unsigned short)s) << 16);
}

// stage a 64x64 f32 tile (row-major, row stride HD) -> bf16 LDS [64][LDT]
__device__ __forceinline__ void stage64(const float* __restrict__ src_base,
                                        short* __restrict__ dst, int tid) {
    const int r = tid >> 2, cg = tid & 3;
    const float4* src = (const float4*)(src_base + (size_t)r * HD + cg * 16);
    float f[16];
#pragma unroll
    for (int t = 0; t < 4; ++t) {
        float4 v4 = src[t];
        f[4*t] = v4.x; f[4*t+1] = v4.y; f[4*t+2] = v4.z; f[4*t+3] = v4.w;
    }
    bf16x8 p0, p1;
#pragma unroll
    for (int t = 0; t < 8; ++t) { p0[t] = f2bf(f[t]); p1[t] = f2bf(f[t+8]); }
    *(bf16x8*)&dst[r * LDT + cg * 16]     = p0;
    *(bf16x8*)&dst[r * LDT + cg * 16 + 8] = p1;
}

// stage G[dd][k] = E[1086 - i0 + j0 - dd][k] (or 0) for dd in [0,128)
__device__ __forceinline__ void stageG(const float* __restrict__ eg,
                                       short* __restrict__ Gs, int tid, int i0, int j0) {
    const int dd = tid >> 1, hf = tid & 1;
    const int e = 1086 - i0 + j0 - dd;
    short* dst = &Gs[dd * LDT + hf * 32];
    if (e >= 0 && e < 1024) {
        const float4* src = (const float4*)(eg + (size_t)e * HD + hf * 32);
#pragma unroll
        for (int u = 0; u < 4; ++u) {
            float4 a = src[2*u], b = src[2*u + 1];
            bf16x8 p;
            p[0] = f2bf(a.x); p[1] = f2bf(a.y); p[2] = f2bf(a.z); p[3] = f2bf(a.w);
            p[4] = f2bf(b.x); p[5] = f2bf(b.y); p[6] = f2bf(b.z); p[7] = f2bf(b.w);
            *(bf16x8*)&dst[u * 8] = p;
        }
    } else {
        bf16x8 z = {0,0,0,0,0,0,0,0};
#pragma unroll
        for (int u = 0; u < 4; ++u) *(bf16x8*)&dst[u * 8] = z;
    }
}

// S = Q@K^T + skewed rel (via T = Q@G^T round-tripped through wave-local LDS), masked
__device__ __forceinline__ void compute_sc(const bf16x8* aq, const short* __restrict__ Ks,
                                           const short* __restrict__ Gs, short* __restrict__ Tw,
                                           int wv, int qd, int c, int i0, int j0, f32x4* sc) {
    f32x4 tc[5];
    const f32x4 zz = {0.f, 0.f, 0.f, 0.f};
#pragma unroll
    for (int ct = 0; ct < 4; ++ct) sc[ct] = zz;
#pragma unroll
    for (int dt = 0; dt < 5; ++dt) tc[dt] = zz;
#pragma unroll
    for (int s = 0; s < 2; ++s) {
        bf16x8 a = aq[s];
#pragma unroll
        for (int ct = 0; ct < 4; ++ct) {
            bf16x8 b = *(const bf16x8*)&Ks[(ct * 16 + c) * LDT + s * 32 + qd * 8];
            sc[ct] = __builtin_amdgcn_mfma_f32_16x16x32_bf16(a, b, sc[ct], 0, 0, 0);
        }
#pragma unroll
        for (int dt = 0; dt < 5; ++dt) {
            bf16x8 g = *(const bf16x8*)&Gs[((wv + dt) * 16 + c) * LDT + s * 32 + qd * 8];
            tc[dt] = __builtin_amdgcn_mfma_f32_16x16x32_bf16(a, g, tc[dt], 0, 0, 0);
        }
    }
    // T C-frag -> wave-local LDS (row = qd*4+reg, local col = dt*16+c)
#pragma unroll
    for (int dt = 0; dt < 5; ++dt)
#pragma unroll
        for (int rg = 0; rg < 4; ++rg)
            Tw[(qd * 4 + rg) * TSTR + dt * 16 + c] = f2bf(tc[dt][rg]);
    // add skewed rel + causal mask
#pragma unroll
    for (int ct = 0; ct < 4; ++ct)
#pragma unroll
        for (int rg = 0; rg < 4; ++rg) {
            const int rl  = qd * 4 + rg;
            const int ddl = rl + 63 - ct * 16 - c;          // in [0,78]
            float sval = sc[ct][rg] + bf2f(Tw[rl * TSTR + ddl]);
            const int ig = i0 + wv * 16 + rl;
            const int jg = j0 + ct * 16 + c;
            sc[ct][rg] = (jg <= ig) ? sval : -3.0e38f;
        }
}

__global__ __launch_bounds__(256, 2)
void relattn(const float* __restrict__ qg, const float* __restrict__ kg,
             const float* __restrict__ vg, const float* __restrict__ eg,
             float* __restrict__ outp)
{
    __shared__ short Qs[64 * LDT];
    __shared__ short Ks[64 * LDT];
    __shared__ short Vt[64 * LDT];     // V transposed: [dim][key]
    __shared__ short Gs[128 * LDT];
    __shared__ short TP[4 * 16 * TSTR]; // per-wave T / P scratch (aliased, wave-local)

    const int tid  = threadIdx.x;
    const int wv   = tid >> 6;
    const int lane = tid & 63;
    const int qd   = lane >> 4;
    const int c    = lane & 15;

    const int bh = blockIdx.x & 15;
    const int qt = 31 - (blockIdx.x >> 4);   // heavy q-tiles dispatched first
    const int i0 = qt * 64;

    float* Wg = outp + OUT0;

    // ---- zero-fill the fully-masked column region of weights ----
    {
        const int z0v = (qt + 1) * 16;   // first float4 column
        for (int r = 0; r < 64; ++r) {
            float4* dst = (float4*)(Wg + ((size_t)(bh * SEQ + i0 + r)) * SEQ);
            for (int jv = z0v + tid; jv < SEQ / 4; jv += 256)
                dst[jv] = make_float4(0.f, 0.f, 0.f, 0.f);
        }
    }

    // ---- stage Q tile, preload A-fragments ----
    stage64(qg + ((size_t)(bh * SEQ + i0)) * HD, Qs, tid);
    __syncthreads();
    bf16x8 aq[2];
#pragma unroll
    for (int s = 0; s < 2; ++s)
        aq[s] = *(const bf16x8*)&Qs[(wv * 16 + c) * LDT + s * 32 + qd * 8];

    short* Tw = &TP[wv * 16 * TSTR];

    float mrun[4], lrun[4];
#pragma unroll
    for (int rg = 0; rg < 4; ++rg) { mrun[rg] = -3.0e38f; lrun[rg] = 0.f; }

    // =================== PASS 1: row max / sum-exp ===================
    for (int kt = 0; kt <= qt; ++kt) {
        const int j0 = kt * 64;
        __syncthreads();
        stage64(kg + ((size_t)(bh * SEQ + j0)) * HD, Ks, tid);
        stageG(eg, Gs, tid, i0, j0);
        __syncthreads();

        f32x4 sc[4];
        compute_sc(aq, Ks, Gs, Tw, wv, qd, c, i0, j0, sc);

#pragma unroll
        for (int rg = 0; rg < 4; ++rg) {
            float mx = fmaxf(fmaxf(sc[0][rg], sc[1][rg]), fmaxf(sc[2][rg], sc[3][rg]));
            mx = fmaxf(mx, __shfl_xor(mx, 1));
            mx = fmaxf(mx, __shfl_xor(mx, 2));
            mx = fmaxf(mx, __shfl_xor(mx, 4));
            mx = fmaxf(mx, __shfl_xor(mx, 8));
            const float mnew = fmaxf(mrun[rg], mx);
            float ss = __expf(sc[0][rg] - mnew) + __expf(sc[1][rg] - mnew)
                     + __expf(sc[2][rg] - mnew) + __expf(sc[3][rg] - mnew);
            ss += __shfl_xor(ss, 1);
            ss += __shfl_xor(ss, 2);
            ss += __shfl_xor(ss, 4);
            ss += __shfl_xor(ss, 8);
            lrun[rg] = lrun[rg] * __expf(mrun[rg] - mnew) + ss;
            mrun[rg] = mnew;
        }
    }

    float linv[4];
#pragma unroll
    for (int rg = 0; rg < 4; ++rg) linv[rg] = 1.0f / lrun[rg];

    f32x4 ob[4];
    {
        const f32x4 zz = {0.f, 0.f, 0.f, 0.f};
#pragma unroll
        for (int dt = 0; dt < 4; ++dt) ob[dt] = zz;
    }

    // =================== PASS 2: write W, accumulate O ===================
    for (int kt = 0; kt <= qt; ++kt) {
        const int j0 = kt * 64;
        __syncthreads();
        stage64(kg + ((size_t)(bh * SEQ + j0)) * HD, Ks, tid);
        stageG(eg, Gs, tid, i0, j0);
        {   // stage V transposed: Vt[dim][key]
            const int r = tid >> 2, cg = tid & 3;
            const float4* src = (const float4*)(vg + ((size_t)(bh * SEQ + j0 + r)) * HD + cg * 16);
            float f[16];
#pragma unroll
            for (int t = 0; t < 4; ++t) {
                float4 v4 = src[t];
                f[4*t] = v4.x; f[4*t+1] = v4.y; f[4*t+2] = v4.z; f[4*t+3] = v4.w;
            }
#pragma unroll
            for (int t = 0; t < 16; ++t) Vt[(cg * 16 + t) * LDT + r] = f2bf(f[t]);
        }
        __syncthreads();

        f32x4 sc[4];
        compute_sc(aq, Ks, Gs, Tw, wv, qd, c, i0, j0, sc);

        // W = exp(S - m) / l  -> global weights + wave-local P (bf16)
#pragma unroll
        for (int rg = 0; rg < 4; ++rg) {
            const int rl = qd * 4 + rg;
            const int ig = i0 + wv * 16 + rl;
            float* wrow = Wg + ((size_t)(bh * SEQ + ig)) * SEQ + j0;
#pragma unroll
            for (int ct = 0; ct < 4; ++ct) {
                const float w = __expf(sc[ct][rg] - mrun[rg]) * linv[rg];
                wrow[ct * 16 + c] = w;
                Tw[rl * PSTR + ct * 16 + c] = f2bf(w);
            }
        }

        // O += P @ V
#pragma unroll
        for (int s = 0; s < 2; ++s) {
            bf16x8 ap = *(const bf16x8*)&Tw[c * PSTR + s * 32 + qd * 8];
#pragma unroll
            for (int dt = 0; dt < 4; ++dt) {
                bf16x8 bv = *(const bf16x8*)&Vt[(dt * 16 + c) * LDT + s * 32 + qd * 8];
                ob[dt] = __builtin_amdgcn_mfma_f32_16x16x32_bf16(ap, bv, ob[dt], 0, 0, 0);
            }
        }
    }

    // ---- write O (already normalized, since P was normalized) ----
#pragma unroll
    for (int dt = 0; dt < 4; ++dt)
#pragma unroll
        for (int rg = 0; rg < 4; ++rg) {
            const int ig = i0 + wv * 16 + qd * 4 + rg;
            outp[((size_t)(bh * SEQ + ig)) * HD + dt * 16 + c] = ob[dt][rg];
        }
}

extern "C" void kernel_launch(void* const* d_in, const int* in_sizes, int n_in,
                              void* d_out, int out_size, void* d_ws, size_t ws_size,
                              hipStream_t stream) {
    const float* q = (const float*)d_in[0];
    const float* k = (const float*)d_in[1];
    const float* v = (const float*)d_in[2];
    const float* e = (const float*)d_in[3];
    // d_in[4] (mask) unused: causality computed from indices
    float* out = (float*)d_out;
    hipLaunchKernelGGL(relattn, dim3(512), dim3(256), 0, stream, q, k, v, e, out);
}